// Round 5
// baseline (224.797 us; speedup 1.0000x reference)
//
#include <hip/hip_runtime.h>
#include <math.h>

#define TAU_F       0.1f
#define EPS_NORM_F  1e-12f
#define EPS_DENOM_F 1e-8f

__device__ __forceinline__ float dot4(float4 a, float4 b) {
    return a.x * b.x + a.y * b.y + a.z * b.z + a.w * b.w;
}

__device__ __forceinline__ const float4* rowptr(int r, int n_hard,
        const float4* __restrict__ hn4, const float4* __restrict__ pos4) {
    return (r < n_hard) ? hn4 + (size_t)r * 128
                        : pos4 + (size_t)(r - n_hard) * 128;
}

// -----------------------------------------------------------------------------
// Main kernel. Wave w owns 9 contiguous rows of the 73728 (hard||pos) rows.
// Hot path: issue all 18 float4 loads (18 KB in flight), fold (dot,norm2)
// partials as data arrives, then ONE 18-chain interleaved butterfly
// (6 dependent levels total for all 9 rows, instead of 3x6).
// Hard-neg rows accumulate exp(cos/tau); positive rows store cos to ws.
// Waves 0..2*n_mix-1 also compute one synthetic negative (self-contained).
// Block partial -> block_sums[blockIdx.x] (no atomics, no init needed).
// -----------------------------------------------------------------------------
__global__ void __launch_bounds__(256) main_kernel(
        const float* __restrict__ anchor,
        const float* __restrict__ pos,
        const float* __restrict__ hn,
        const int* __restrict__ mix_idx,
        const int* __restrict__ idx_a,
        const int* __restrict__ idx_b,
        const float* __restrict__ alpha_raw,
        const float* __restrict__ beta_raw,
        double* __restrict__ block_sums,
        float* __restrict__ cos_p,
        int n_hard, int n_pos, int n_mix) {
    const int lane = threadIdx.x & 63;
    const int wib  = threadIdx.x >> 6;
    const int wpb  = blockDim.x >> 6;
    const int wid  = blockIdx.x * wpb + wib;
    const int nw   = gridDim.x * wpb;

    const float4* hn4  = (const float4*)hn;
    const float4* pos4 = (const float4*)pos;

    // Anchor slice: 64 lanes tile all 512 floats (2 float4 each).
    const float4* a4 = (const float4*)anchor;
    const float4 a0 = a4[lane];
    const float4 a1 = a4[lane + 64];
    float na2 = dot4(a0, a0) + dot4(a1, a1);
    #pragma unroll
    for (int o = 32; o > 0; o >>= 1) na2 += __shfl_xor(na2, o, 64);
    const float na = fmaxf(sqrtf(na2), EPS_NORM_F);

    const int total = n_hard + n_pos;
    const int per   = (total + nw - 1) / nw;     // 9 for the bench shape
    const int base  = wid * per;

    float local_exp = 0.0f;   // lane-uniform after each butterfly reduce

    if (per == 9 && base + 9 <= total) {
        // ---- hot path: 9 rows, all loads in flight, one merged butterfly ----
        float s[9], q[9];
        {
            float4 v0[9], v1[9];
            #pragma unroll
            for (int r = 0; r < 9; ++r) {
                const float4* P = rowptr(base + r, n_hard, hn4, pos4);
                v0[r] = P[lane];
                v1[r] = P[lane + 64];
            }
            #pragma unroll
            for (int r = 0; r < 9; ++r) {
                s[r] = dot4(v0[r], a0) + dot4(v1[r], a1);
                q[r] = dot4(v0[r], v0[r]) + dot4(v1[r], v1[r]);
            }
        }
        // 18 interleaved butterfly chains, 6 dependent levels total.
        #pragma unroll
        for (int o = 32; o > 0; o >>= 1) {
            #pragma unroll
            for (int r = 0; r < 9; ++r) {
                s[r] += __shfl_xor(s[r], o, 64);
                q[r] += __shfl_xor(q[r], o, 64);
            }
        }
        #pragma unroll
        for (int r = 0; r < 9; ++r) {
            const float c  = s[r] / (fmaxf(sqrtf(q[r]), EPS_NORM_F) * na);
            const int   rr = base + r;
            if (rr < n_hard) local_exp += expf(c / TAU_F);
            else if (lane == 0) cos_p[rr - n_hard] = c;
        }
    } else {
        // ---- generic fallback (unused for the benchmark shape) ----
        for (int it = 0; it < per; ++it) {
            const int r = base + it;
            if (r >= total) break;
            const float4* P = rowptr(r, n_hard, hn4, pos4);
            const float4 v0 = P[lane], v1 = P[lane + 64];
            float s  = dot4(v0, a0) + dot4(v1, a1);
            float q  = dot4(v0, v0) + dot4(v1, v1);
            #pragma unroll
            for (int o = 32; o > 0; o >>= 1) {
                s += __shfl_xor(s, o, 64);  q += __shfl_xor(q, o, 64);
            }
            const float c = s / (fmaxf(sqrtf(q), EPS_NORM_F) * na);
            if (r < n_hard) local_exp += expf(c / TAU_F);
            else if (lane == 0) cos_p[r - n_hard] = c;
        }
    }

    // ---- Synthetic negatives: one wave per item, self-contained math ----
    if (wid < n_mix) {
        const int j = wid;
        const float4* R = hn4 + (size_t)mix_idx[j] * 128;
        const float4 v0 = R[lane], v1 = R[lane + 64];
        float s  = dot4(v0, a0) + dot4(v1, a1);
        float n2 = dot4(v0, v0) + dot4(v1, v1);
        #pragma unroll
        for (int o = 32; o > 0; o >>= 1) {
            s  += __shfl_xor(s,  o, 64);
            n2 += __shfl_xor(n2, o, 64);
        }
        const float nrm = fmaxf(sqrtf(n2), EPS_NORM_F);
        const float c   = s / (nrm * na);
        const float al  = alpha_raw[j] * 0.4f + 0.1f;
        const float num  = (1.0f - al) * c + al;
        const float den2 = (1.0f - al) * (1.0f - al) + al * al
                         + 2.0f * al * (1.0f - al) * c;
        const float cosm = num / fmaxf(sqrtf(den2), EPS_NORM_F);
        local_exp += expf(cosm / TAU_F);
    } else if (wid < 2 * n_mix) {
        const int k  = wid - n_mix;
        const float4* A = hn4 + (size_t)idx_a[k] * 128;
        const float4* B = hn4 + (size_t)idx_b[k] * 128;
        const float4 x0 = A[lane], x1 = A[lane + 64];
        const float4 y0 = B[lane], y1 = B[lane + 64];
        float sa  = dot4(x0, a0) + dot4(x1, a1);
        float sb  = dot4(y0, a0) + dot4(y1, a1);
        float d   = dot4(x0, y0) + dot4(x1, y1);
        float nA2 = dot4(x0, x0) + dot4(x1, x1);
        float nB2 = dot4(y0, y0) + dot4(y1, y1);
        #pragma unroll
        for (int o = 32; o > 0; o >>= 1) {
            sa  += __shfl_xor(sa,  o, 64);
            sb  += __shfl_xor(sb,  o, 64);
            d   += __shfl_xor(d,   o, 64);
            nA2 += __shfl_xor(nA2, o, 64);
            nB2 += __shfl_xor(nB2, o, 64);
        }
        const float nA  = fmaxf(sqrtf(nA2), EPS_NORM_F);
        const float nB  = fmaxf(sqrtf(nB2), EPS_NORM_F);
        const float ca  = sa / (nA * na);
        const float cb  = sb / (nB * na);
        const float dab = d  / (nA * nB);
        const float be  = beta_raw[k] * 0.4f + 0.3f;
        const float num  = be * ca + (1.0f - be) * cb;
        const float den2 = be * be + (1.0f - be) * (1.0f - be)
                         + 2.0f * be * (1.0f - be) * dab;
        const float cosm = num / fmaxf(sqrtf(den2), EPS_NORM_F);
        local_exp += expf(cosm / TAU_F);
    }

    // ---- Block partial -> block_sums[blockIdx.x] (no atomic, no init) ----
    __shared__ float sred[16];
    if (lane == 0) sred[wib] = local_exp;
    __syncthreads();
    if (threadIdx.x == 0) {
        float t = 0.0f;
        for (int i = 0; i < wpb; ++i) t += sred[i];
        block_sums[blockIdx.x] = (double)t;
    }
}

// -----------------------------------------------------------------------------
// Finish kernel (1 block, 1024 threads): S = sum(block_sums);
// loss = mean_i [ -log(pv_i / (pv_i + S + 1e-8)) ].
// cos_p read as float4 (n_pos = 8192 -> 2048 float4, 2 per thread).
// -----------------------------------------------------------------------------
__global__ void __launch_bounds__(1024) finish_kernel(
        const double* __restrict__ block_sums, int nblocks,
        const float* __restrict__ cos_p, int n_pos,
        float* __restrict__ out) {
    __shared__ double sred[1024];
    double acc = 0.0;
    for (int i = threadIdx.x; i < nblocks; i += 1024) acc += block_sums[i];
    sred[threadIdx.x] = acc;
    __syncthreads();
    for (int s = 512; s > 0; s >>= 1) {
        if (threadIdx.x < (unsigned)s) sred[threadIdx.x] += sred[threadIdx.x + s];
        __syncthreads();
    }
    const float S = (float)sred[0];
    __syncthreads();

    double lacc = 0.0;
    const int n4 = n_pos >> 2;
    const float4* cp4 = (const float4*)cos_p;
    for (int i = threadIdx.x; i < n4; i += 1024) {
        const float4 c = cp4[i];
        const float pv0 = expf(c.x / TAU_F);
        const float pv1 = expf(c.y / TAU_F);
        const float pv2 = expf(c.z / TAU_F);
        const float pv3 = expf(c.w / TAU_F);
        lacc += (double)(-logf(pv0 / (pv0 + S + EPS_DENOM_F)));
        lacc += (double)(-logf(pv1 / (pv1 + S + EPS_DENOM_F)));
        lacc += (double)(-logf(pv2 / (pv2 + S + EPS_DENOM_F)));
        lacc += (double)(-logf(pv3 / (pv3 + S + EPS_DENOM_F)));
    }
    for (int i = (n4 << 2) + threadIdx.x; i < n_pos; i += 1024) {
        const float pv = expf(cos_p[i] / TAU_F);
        lacc += (double)(-logf(pv / (pv + S + EPS_DENOM_F)));
    }
    sred[threadIdx.x] = lacc;
    __syncthreads();
    for (int s = 512; s > 0; s >>= 1) {
        if (threadIdx.x < (unsigned)s) sred[threadIdx.x] += sred[threadIdx.x + s];
        __syncthreads();
    }
    if (threadIdx.x == 0) out[0] = (float)(sred[0] / (double)n_pos);
}

extern "C" void kernel_launch(void* const* d_in, const int* in_sizes, int n_in,
                              void* d_out, int out_size, void* d_ws, size_t ws_size,
                              hipStream_t stream) {
    const float* anchor    = (const float*)d_in[0];
    const float* positives = (const float*)d_in[1];
    const float* hardnegs  = (const float*)d_in[2];
    const int*   mix_idx   = (const int*)d_in[3];
    const int*   idx_a     = (const int*)d_in[4];
    const int*   idx_b     = (const int*)d_in[5];
    const float* alpha_raw = (const float*)d_in[6];
    const float* beta_raw  = (const float*)d_in[7];

    const int D      = in_sizes[0];          // 512
    const int n_pos  = in_sizes[1] / D;      // 8192
    const int n_hard = in_sizes[2] / D;      // 65536
    const int n_mix  = in_sizes[3];          // 64

    const int GRID = 2048;                   // 8192 waves -> 9 rows/wave exactly

    // ws layout: [0, GRID*8) block_sums | then cos_p (16B-aligned).
    // Both fully overwritten every launch (ws poison needs no init).
    char*   ws         = (char*)d_ws;
    double* block_sums = (double*)ws;
    float*  cos_p      = (float*)(ws + (size_t)GRID * sizeof(double));

    main_kernel<<<GRID, 256, 0, stream>>>(anchor, positives, hardnegs,
                                          mix_idx, idx_a, idx_b,
                                          alpha_raw, beta_raw,
                                          block_sums, cos_p,
                                          n_hard, n_pos, n_mix);

    finish_kernel<<<1, 1024, 0, stream>>>(block_sums, GRID, cos_p,
                                          n_pos, (float*)d_out);
}

// Round 7
// 220.579 us; speedup vs baseline: 1.0191x; 1.0191x over previous
//
#include <hip/hip_runtime.h>
#include <math.h>

#define TAU_F       0.1f
#define EPS_NORM_F  1e-12f
#define EPS_DENOM_F 1e-8f

__device__ __forceinline__ float dot4(float4 a, float4 b) {
    return a.x * b.x + a.y * b.y + a.z * b.z + a.w * b.w;
}

__device__ __forceinline__ const float4* rowptr(int r, int n_hard,
        const float4* __restrict__ hn4, const float4* __restrict__ pos4) {
    return (r < n_hard) ? hn4 + (size_t)r * 128
                        : pos4 + (size_t)(r - n_hard) * 128;
}

// -----------------------------------------------------------------------------
// Main kernel. Wave w owns 3 contiguous rows of the 73728 (hard||pos) rows.
// 24576 waves (6144 blocks x 4): low VGPR (~<=64) -> full 32-waves/CU
// occupancy; continuous HBM issuance via block turnover instead of two big
// drain-synchronized rounds. Hot path: 6 independent float4 loads, one
// 6-chain interleaved butterfly. Hard-neg rows accumulate exp(cos/tau);
// positive rows store cos. Waves 0..2*n_mix-1 also compute one synthetic
// negative. Block partial -> block_sums[blockIdx.x] (no atomics, no init).
// -----------------------------------------------------------------------------
__global__ void __launch_bounds__(256) main_kernel(
        const float* __restrict__ anchor,
        const float* __restrict__ pos,
        const float* __restrict__ hn,
        const int* __restrict__ mix_idx,
        const int* __restrict__ idx_a,
        const int* __restrict__ idx_b,
        const float* __restrict__ alpha_raw,
        const float* __restrict__ beta_raw,
        double* __restrict__ block_sums,
        float* __restrict__ cos_p,
        int n_hard, int n_pos, int n_mix) {
    const int lane = threadIdx.x & 63;
    const int wib  = threadIdx.x >> 6;
    const int wpb  = blockDim.x >> 6;
    const int wid  = blockIdx.x * wpb + wib;
    const int nw   = gridDim.x * wpb;

    const float4* hn4  = (const float4*)hn;
    const float4* pos4 = (const float4*)pos;

    // Anchor slice: 64 lanes tile all 512 floats (2 float4 each).
    const float4* a4 = (const float4*)anchor;
    const float4 a0 = a4[lane];
    const float4 a1 = a4[lane + 64];
    float na2 = dot4(a0, a0) + dot4(a1, a1);
    #pragma unroll
    for (int o = 32; o > 0; o >>= 1) na2 += __shfl_xor(na2, o, 64);
    const float na = fmaxf(sqrtf(na2), EPS_NORM_F);

    const int total = n_hard + n_pos;
    const int per   = (total + nw - 1) / nw;     // 3 for the bench shape
    const int base  = wid * per;

    float local_exp = 0.0f;   // lane-uniform after each butterfly reduce

    if (per == 3 && base + 3 <= total) {
        // ---- hot path: 3 rows, 6 loads in flight, one merged butterfly ----
        float s[3], q[3];
        {
            float4 v0[3], v1[3];
            #pragma unroll
            for (int r = 0; r < 3; ++r) {
                const float4* P = rowptr(base + r, n_hard, hn4, pos4);
                v0[r] = P[lane];
                v1[r] = P[lane + 64];
            }
            #pragma unroll
            for (int r = 0; r < 3; ++r) {
                s[r] = dot4(v0[r], a0) + dot4(v1[r], a1);
                q[r] = dot4(v0[r], v0[r]) + dot4(v1[r], v1[r]);
            }
        }
        // 6 interleaved butterfly chains, 6 dependent levels total.
        #pragma unroll
        for (int o = 32; o > 0; o >>= 1) {
            #pragma unroll
            for (int r = 0; r < 3; ++r) {
                s[r] += __shfl_xor(s[r], o, 64);
                q[r] += __shfl_xor(q[r], o, 64);
            }
        }
        #pragma unroll
        for (int r = 0; r < 3; ++r) {
            const float c  = s[r] / (fmaxf(sqrtf(q[r]), EPS_NORM_F) * na);
            const int   rr = base + r;
            if (rr < n_hard) local_exp += expf(c / TAU_F);
            else if (lane == 0) cos_p[rr - n_hard] = c;
        }
    } else {
        // ---- generic fallback (unused for the benchmark shape) ----
        for (int it = 0; it < per; ++it) {
            const int r = base + it;
            if (r >= total) break;
            const float4* P = rowptr(r, n_hard, hn4, pos4);
            const float4 v0 = P[lane], v1 = P[lane + 64];
            float s  = dot4(v0, a0) + dot4(v1, a1);
            float q  = dot4(v0, v0) + dot4(v1, v1);
            #pragma unroll
            for (int o = 32; o > 0; o >>= 1) {
                s += __shfl_xor(s, o, 64);  q += __shfl_xor(q, o, 64);
            }
            const float c = s / (fmaxf(sqrtf(q), EPS_NORM_F) * na);
            if (r < n_hard) local_exp += expf(c / TAU_F);
            else if (lane == 0) cos_p[r - n_hard] = c;
        }
    }

    // ---- Synthetic negatives: one wave per item, self-contained math ----
    if (wid < n_mix) {
        const int j = wid;
        const float4* R = hn4 + (size_t)mix_idx[j] * 128;
        const float4 v0 = R[lane], v1 = R[lane + 64];
        float s  = dot4(v0, a0) + dot4(v1, a1);
        float n2 = dot4(v0, v0) + dot4(v1, v1);
        #pragma unroll
        for (int o = 32; o > 0; o >>= 1) {
            s  += __shfl_xor(s,  o, 64);
            n2 += __shfl_xor(n2, o, 64);
        }
        const float nrm = fmaxf(sqrtf(n2), EPS_NORM_F);
        const float c   = s / (nrm * na);
        const float al  = alpha_raw[j] * 0.4f + 0.1f;
        const float num  = (1.0f - al) * c + al;
        const float den2 = (1.0f - al) * (1.0f - al) + al * al
                         + 2.0f * al * (1.0f - al) * c;
        const float cosm = num / fmaxf(sqrtf(den2), EPS_NORM_F);
        local_exp += expf(cosm / TAU_F);
    } else if (wid < 2 * n_mix) {
        const int k  = wid - n_mix;
        const float4* A = hn4 + (size_t)idx_a[k] * 128;
        const float4* B = hn4 + (size_t)idx_b[k] * 128;
        const float4 x0 = A[lane], x1 = A[lane + 64];
        const float4 y0 = B[lane], y1 = B[lane + 64];
        float sa  = dot4(x0, a0) + dot4(x1, a1);
        float sb  = dot4(y0, a0) + dot4(y1, a1);
        float d   = dot4(x0, y0) + dot4(x1, y1);
        float nA2 = dot4(x0, x0) + dot4(x1, x1);
        float nB2 = dot4(y0, y0) + dot4(y1, y1);
        #pragma unroll
        for (int o = 32; o > 0; o >>= 1) {
            sa  += __shfl_xor(sa,  o, 64);
            sb  += __shfl_xor(sb,  o, 64);
            d   += __shfl_xor(d,   o, 64);
            nA2 += __shfl_xor(nA2, o, 64);
            nB2 += __shfl_xor(nB2, o, 64);
        }
        const float nA  = fmaxf(sqrtf(nA2), EPS_NORM_F);
        const float nB  = fmaxf(sqrtf(nB2), EPS_NORM_F);
        const float ca  = sa / (nA * na);
        const float cb  = sb / (nB * na);
        const float dab = d  / (nA * nB);
        const float be  = beta_raw[k] * 0.4f + 0.3f;
        const float num  = be * ca + (1.0f - be) * cb;
        const float den2 = be * be + (1.0f - be) * (1.0f - be)
                         + 2.0f * be * (1.0f - be) * dab;
        const float cosm = num / fmaxf(sqrtf(den2), EPS_NORM_F);
        local_exp += expf(cosm / TAU_F);
    }

    // ---- Block partial -> block_sums[blockIdx.x] (no atomic, no init) ----
    __shared__ float sred[16];
    if (lane == 0) sred[wib] = local_exp;
    __syncthreads();
    if (threadIdx.x == 0) {
        float t = 0.0f;
        for (int i = 0; i < wpb; ++i) t += sred[i];
        block_sums[blockIdx.x] = (double)t;
    }
}

// -----------------------------------------------------------------------------
// Finish kernel (1 block, 1024 threads): S = sum(block_sums);
// loss = mean_i [ -log(pv_i / (pv_i + S + 1e-8)) ].
// -----------------------------------------------------------------------------
__global__ void __launch_bounds__(1024) finish_kernel(
        const double* __restrict__ block_sums, int nblocks,
        const float* __restrict__ cos_p, int n_pos,
        float* __restrict__ out) {
    __shared__ double sred[1024];
    double acc = 0.0;
    for (int i = threadIdx.x; i < nblocks; i += 1024) acc += block_sums[i];
    sred[threadIdx.x] = acc;
    __syncthreads();
    for (int s = 512; s > 0; s >>= 1) {
        if (threadIdx.x < (unsigned)s) sred[threadIdx.x] += sred[threadIdx.x + s];
        __syncthreads();
    }
    const float S = (float)sred[0];
    __syncthreads();

    double lacc = 0.0;
    const int n4 = n_pos >> 2;
    const float4* cp4 = (const float4*)cos_p;
    for (int i = threadIdx.x; i < n4; i += 1024) {
        const float4 c = cp4[i];
        const float pv0 = expf(c.x / TAU_F);
        const float pv1 = expf(c.y / TAU_F);
        const float pv2 = expf(c.z / TAU_F);
        const float pv3 = expf(c.w / TAU_F);
        lacc += (double)(-logf(pv0 / (pv0 + S + EPS_DENOM_F)));
        lacc += (double)(-logf(pv1 / (pv1 + S + EPS_DENOM_F)));
        lacc += (double)(-logf(pv2 / (pv2 + S + EPS_DENOM_F)));
        lacc += (double)(-logf(pv3 / (pv3 + S + EPS_DENOM_F)));
    }
    for (int i = (n4 << 2) + threadIdx.x; i < n_pos; i += 1024) {
        const float pv = expf(cos_p[i] / TAU_F);
        lacc += (double)(-logf(pv / (pv + S + EPS_DENOM_F)));
    }
    sred[threadIdx.x] = lacc;
    __syncthreads();
    for (int s = 512; s > 0; s >>= 1) {
        if (threadIdx.x < (unsigned)s) sred[threadIdx.x] += sred[threadIdx.x + s];
        __syncthreads();
    }
    if (threadIdx.x == 0) out[0] = (float)(sred[0] / (double)n_pos);
}

extern "C" void kernel_launch(void* const* d_in, const int* in_sizes, int n_in,
                              void* d_out, int out_size, void* d_ws, size_t ws_size,
                              hipStream_t stream) {
    const float* anchor    = (const float*)d_in[0];
    const float* positives = (const float*)d_in[1];
    const float* hardnegs  = (const float*)d_in[2];
    const int*   mix_idx   = (const int*)d_in[3];
    const int*   idx_a     = (const int*)d_in[4];
    const int*   idx_b     = (const int*)d_in[5];
    const float* alpha_raw = (const float*)d_in[6];
    const float* beta_raw  = (const float*)d_in[7];

    const int D      = in_sizes[0];          // 512
    const int n_pos  = in_sizes[1] / D;      // 8192
    const int n_hard = in_sizes[2] / D;      // 65536
    const int n_mix  = in_sizes[3];          // 64

    const int GRID = 6144;                   // 24576 waves -> 3 rows/wave exactly

    // ws layout: [0, GRID*8) block_sums | then cos_p (16B-aligned).
    // Both fully overwritten every launch (ws poison needs no init).
    char*   ws         = (char*)d_ws;
    double* block_sums = (double*)ws;
    float*  cos_p      = (float*)(ws + (size_t)GRID * sizeof(double));

    main_kernel<<<GRID, 256, 0, stream>>>(anchor, positives, hardnegs,
                                          mix_idx, idx_a, idx_b,
                                          alpha_raw, beta_raw,
                                          block_sums, cos_p,
                                          n_hard, n_pos, n_mix);

    finish_kernel<<<1, 1024, 0, stream>>>(block_sums, GRID, cos_p,
                                          n_pos, (float*)d_out);
}